// Round 6
// baseline (2472.655 us; speedup 1.0000x reference)
//
#include <hip/hip_runtime.h>

// LSTM: B=128, S=256, I=512, H=1024, O=512.
// R14 = R13 minus the ENTIRE flag protocol in rot mode: FLAGLESS SELF-
// VALIDATING PUBLISH.
//  Mechanism: f2bf reserves bf16 0x0000 ("not yet written"): +0 remaps to
//  0x0001 (1e-38, no practical error). Every published 32-bit word is
//  nonzero once its store lands. A consumer h-fragment (16B) is exactly one
//  producer store; validity = all 4 words nonzero (needs only per-word
//  atomicity). Consumers UC-load (sc0 sc1, bypass L1/L2) their 32 frags and
//  retry invalid ones until all valid -- the chain becomes ONE one-way
//  fabric trip (producer store -> LLC -> consumer retry-load) instead of
//  publish-ack RT + flag RT + poll-detect RT + fetch RT.
//  Producer: publish stores fire-and-forget (no vmcnt, no atomicAdd); the
//  store drain overlaps wave0's next x-phase, OFF the global chain.
//  Rot arena pre-zeroed in prep each launch (buffer0 = 0x00010001 encoded
//  zeros for h_0; kernel-boundary L2 flush makes zeros LLC-visible).
//  Epilogue: final flag barrier replaced by the same validity-retry on the
//  step-256 buffer. 2 syncthreads/step (was 3). Non-rot keeps old flags.
// 256 blocks x 256 thr: block = (rq = blockIdx>>6: rows rq*32..+31,
// cg = blockIdx&63: gate-cols cg*64..+63). Wave (ct = w&1, kh = w>>1).

#define B_ 128
#define S_ 256
#define I_ 512
#define H_ 1024
#define O_ 512

typedef unsigned short u16;
typedef unsigned int u32;
typedef unsigned long long u64;

typedef short v8s __attribute__((ext_vector_type(8)));
typedef unsigned int v4u __attribute__((ext_vector_type(4)));
typedef float v16f __attribute__((ext_vector_type(16)));
typedef float v4f __attribute__((ext_vector_type(4)));

__device__ __forceinline__ u16 f2bf(float f) {
  u32 u = __float_as_uint(f);
  u32 r = (u + 0x7fffu + ((u >> 16) & 1u)) >> 16;   // RNE
  r += (r == 0u);   // reserve 0x0000 as "not written"; +0 -> 0x0001 (1e-38)
  return (u16)r;
}
__device__ __forceinline__ u32 pack2(float a, float b) {
  return (u32)f2bf(a) | ((u32)f2bf(b) << 16);
}
__device__ __forceinline__ uint4 cvt8(const float* __restrict__ s) {
  float4 f0 = ((const float4*)s)[0];
  float4 f1 = ((const float4*)s)[1];
  uint4 o;
  o.x = pack2(f0.x, f0.y); o.y = pack2(f0.z, f0.w);
  o.z = pack2(f1.x, f1.y); o.w = pack2(f1.z, f1.w);
  return o;
}

__device__ __forceinline__ uint4 uc_ld16(const u16* p) {
  u64 lo = __hip_atomic_load((const u64*)p, __ATOMIC_RELAXED, __HIP_MEMORY_SCOPE_AGENT);
  u64 hi = __hip_atomic_load((const u64*)p + 1, __ATOMIC_RELAXED, __HIP_MEMORY_SCOPE_AGENT);
  uint4 v; v.x = (u32)lo; v.y = (u32)(lo >> 32); v.z = (u32)hi; v.w = (u32)(hi >> 32);
  return v;
}
// Agent-visible 16B publish store: plain dwordx4, write-through (sc0 sc1).
__device__ __forceinline__ void uc_st16(u16* p, uint4 v) {
  v4u d;
  d.x = v.x; d.y = v.y; d.z = v.z; d.w = v.w;
  asm volatile("global_store_dwordx4 %0, %1, off sc0 sc1"
               :: "v"(p), "v"(d) : "memory");
}

// ---------------------------------------------------------------- prep ----
__global__ void lstm_prep(
    const float* __restrict__ x,
    const float* __restrict__ Whf, const float* __restrict__ Whi,
    const float* __restrict__ Whg, const float* __restrict__ Who,
    const float* __restrict__ Wxf, const float* __restrict__ Wxi,
    const float* __restrict__ Wxg, const float* __restrict__ Wxo,
    const float* __restrict__ bfp, const float* __restrict__ bip,
    const float* __restrict__ bgp, const float* __restrict__ bop,
    const float* __restrict__ Why,
    u16* __restrict__ xt, u16* __restrict__ Wc, float* __restrict__ bc,
    u16* __restrict__ WhyT, u16* __restrict__ hbuf, u32* __restrict__ barrier,
    int rotFlag)
{
  const int gid = blockIdx.x * blockDim.x + threadIdx.x;
  const int gsz = gridDim.x * blockDim.x;

  if (gid < 256) barrier[gid] = 0u;

  // xA[t][rq][w8 0..63][row 0..31] (16B units) <- x[b=rq*32+row][t][w8*8..+8]
  for (int v = gid; v < (S_ * B_ * I_ / 8); v += gsz) {
    int flat = v * 8;
    int b = flat / (S_ * I_);
    int rem = flat - b * (S_ * I_);
    int t = rem / I_;
    int i = rem - t * I_;
    size_t dst = ((size_t)(t * 4 + (b >> 5)) * 64 + (i >> 3)) * 32 + (b & 31);
    ((uint4*)xt)[dst] = cvt8(x + flat);
  }

  // WcF[w8 0..191][colG 0..4095]: w8<64 -> Wx k=w8*8 ; w8>=64 -> Wh k=(w8-64)*8
  for (int o = gid; o < 192 * 4096; o += gsz) {
    int w8 = o >> 12;
    int colG = o & 4095;
    int unit = ((colG >> 6) << 4) + (((colG >> 5) & 1) << 3) + ((colG >> 2) & 7);
    int g = colG & 3;
    const float* Whp = (g == 0) ? Whf : (g == 1) ? Whi : (g == 2) ? Whg : Who;
    const float* Wxp = (g == 0) ? Wxf : (g == 1) ? Wxi : (g == 2) ? Wxg : Wxo;
    const float* s = (w8 < 64) ? (Wxp + (size_t)unit * 512 + w8 * 8)
                               : (Whp + (size_t)unit * 1024 + (w8 - 64) * 8);
    ((uint4*)Wc)[o] = cvt8(s);
  }

  // bias (colG-indexed)
  for (int n = gid; n < 4096; n += gsz) {
    int unit = ((n >> 6) << 4) + (((n >> 5) & 1) << 3) + ((n >> 2) & 7);
    int g = n & 3;
    const float* bp = (g == 0) ? bfp : (g == 1) ? bip : (g == 2) ? bgp : bop;
    bc[n] = bp[unit];
  }

  // Why -> bf16 (row-major [o][k])
  for (int v = gid; v < (O_ * H_ / 8); v += gsz) {
    int flat = v * 8;
    *(uint4*)(WhyT + flat) = cvt8(Why + flat);
  }

  // rot: buffer0 = encoded zeros (0x0001 bf16, h_0 ~= 0), buffers 1..256 = 0
  // ("not yet written"). non-rot: plain-zero hA[0], hA[1] (old flag path).
  if (rotFlag) {
    for (int v = gid; v < 257 * 16384; v += gsz) {
      u32 wv = (v < 16384) ? 0x00010001u : 0u;
      uint4 z; z.x = wv; z.y = wv; z.z = wv; z.w = wv;
      ((uint4*)hbuf)[v] = z;
    }
  } else {
    for (int v = gid; v < 2 * 16384; v += gsz) {
      uint4 z; z.x = 0; z.y = 0; z.z = 0; z.w = 0;
      ((uint4*)hbuf)[v] = z;
    }
  }
}

// ------------------------------------------------------ persistent LSTM ----
__global__ __launch_bounds__(256, 1) void lstm_seq(
    const u16* __restrict__ xt, const u16* __restrict__ Wc,
    const float* __restrict__ bc, u16* __restrict__ hbuf,
    const u16* __restrict__ WhyT, const float* __restrict__ WhyB,
    float* __restrict__ out, u32* __restrict__ barrier, int rotFlag)
{
  __shared__ float scr[2048];   // cross-kh partial-sum exchange (8 KB)
  __shared__ u16 hstage[512];   // h gather tile: [row 0..31][unitL 0..15]

  const int tid  = threadIdx.x;
  const int lane = tid & 63;
  const int w    = tid >> 6;
  const int ct   = w & 1;             // col tile (32 cols)
  const int kh   = w >> 1;            // K half
  const int rq   = blockIdx.x >> 6;   // rows rq*32..+31
  const int cg   = blockIdx.x & 63;   // gate-cols cg*64..+63
  const bool rot = (rotFlag != 0);

  const int colN  = lane & 31;
  const int kgsel = lane >> 5;
  const int colG  = cg * 64 + ct * 32 + colN;
  const int gate  = colN & 3;                 // 0=f 1=i 2=g 3=o
  const int unitL = ct * 8 + (colN >> 2);
  const float bias = bc[colG];

  const uint4* xA4  = (const uint4*)xt;
  const uint4* WcF4 = (const uint4*)Wc;
  uint4*       HA4  = (uint4*)hbuf;

  const int xaOff = rq * 2048 + kh * 1024 + lane;                 // + t*8192 + kb*64
  const int xbOff = kh * 131072 + kgsel * 4096 + colG;            // + kb*8192
  const int haOff = rq * 4096 + kh * 2048 + lane;                 // + tb + kb*64
  const int hbOff = 262144 + kh * 262144 + kgsel * 4096 + colG;   // + kb*8192

  float c[8];
#pragma unroll
  for (int i = 0; i < 8; ++i) c[i] = 0.f;

  // One-time acquire: drop stale lines so cached reads (weights, x) and the
  // UC protocol state are correct.
  __builtin_amdgcn_fence(__ATOMIC_ACQUIRE, "agent");
  __syncthreads();

  // ---- park ALL weight B-frags in registers (192 regs/lane, AV->AGPR) ----
  v8s Bx[16], Bh[32];
  {
    const uint4* bx = WcF4 + xbOff;
#pragma unroll
    for (int kb = 0; kb < 16; ++kb)
      Bx[kb] = __builtin_bit_cast(v8s, bx[(size_t)kb * 8192]);
    const uint4* bh = WcF4 + hbOff;
#pragma unroll
    for (int kb = 0; kb < 32; ++kb)
      Bh[kb] = __builtin_bit_cast(v8s, bh[(size_t)kb * 8192]);
  }

  v16f acc0, acc1;

#pragma unroll 1
  for (int t = 0; t < S_; ++t) {
    const size_t tb = rot ? (size_t)t * 16384 : (size_t)(t & 1) * 16384;
    const size_t tn = rot ? (size_t)(t + 1) * 16384 : (size_t)((t & 1) ^ 1) * 16384;

#pragma unroll
    for (int i = 0; i < 16; ++i) { acc0[i] = 0.f; acc1[i] = 0.f; }

    // ---- x-phase: burst-load 16 A-frags, then MFMA against parked Bx ----
    {
      const uint4* ax = xA4 + (size_t)t * 8192 + xaOff;
      v8s xr[16];
#pragma unroll
      for (int kb = 0; kb < 16; ++kb)
        xr[kb] = __builtin_bit_cast(v8s, ax[kb * 64]);
#pragma unroll
      for (int kb = 0; kb < 16; ++kb) {
        if (kb & 1) acc1 = __builtin_amdgcn_mfma_f32_32x32x16_bf16(xr[kb], Bx[kb], acc1, 0, 0, 0);
        else        acc0 = __builtin_amdgcn_mfma_f32_32x32x16_bf16(xr[kb], Bx[kb], acc0, 0, 0, 0);
      }
    }

    // ---- h-phase ----
    v8s hr[32];
    if (rot) {
      // FLAGLESS: UC burst + per-frag validity retry (word != 0).
      const uint4* ah = HA4 + tb + haOff;
      v4u t0[32];
#pragma unroll
      for (int kb = 0; kb < 32; ++kb)
        asm volatile("global_load_dwordx4 %0, %1, off sc0 sc1"
                     : "=v"(t0[kb]) : "v"((const u16*)(ah + kb * 64)) : "memory");
      asm volatile("s_waitcnt vmcnt(0)" ::: "memory");
      __builtin_amdgcn_sched_barrier(0);
      u32 need = 0xffffffffu;
      u32 spins = 0;
      for (;;) {
#pragma unroll
        for (int kb = 0; kb < 32; ++kb)
          if ((need >> kb) & 1u) {
            int ok = (t0[kb].x != 0u) & (t0[kb].y != 0u) &
                     (t0[kb].z != 0u) & (t0[kb].w != 0u);
            if (__all(ok)) need &= ~(1u << kb);
          }
        if (!need || ++spins > (1u << 20)) break;
#pragma unroll
        for (int kb = 0; kb < 32; ++kb)
          if ((need >> kb) & 1u)
            asm volatile("global_load_dwordx4 %0, %1, off sc0 sc1"
                         : "=v"(t0[kb]) : "v"((const u16*)(ah + kb * 64)) : "memory");
        asm volatile("s_waitcnt vmcnt(0)" ::: "memory");
        __builtin_amdgcn_sched_barrier(0);
      }
#pragma unroll
      for (int kb = 0; kb < 32; ++kb)
        hr[kb] = __builtin_bit_cast(v8s, t0[kb]);
    } else {
      // fallback: old flag wait + UC loads
      if (t > 0) {
        if (tid == 0) {
          u32 spins = 0;
          while (__hip_atomic_load(&barrier[rq * 64], __ATOMIC_RELAXED,
                                   __HIP_MEMORY_SCOPE_AGENT) < 64u * (u32)t) {
            __builtin_amdgcn_s_sleep(1);
            if (++spins > (1u << 22)) break;
          }
        }
        __syncthreads();
      }
      const uint4* ah = HA4 + tb + haOff;
#pragma unroll
      for (int kb = 0; kb < 32; ++kb)
        hr[kb] = __builtin_bit_cast(v8s, uc_ld16((const u16*)(ah + kb * 64)));
    }

#pragma unroll
    for (int kb = 0; kb < 32; ++kb) {
      if (kb & 1) acc1 = __builtin_amdgcn_mfma_f32_32x32x16_bf16(hr[kb], Bh[kb], acc1, 0, 0, 0);
      else        acc0 = __builtin_amdgcn_mfma_f32_32x32x16_bf16(hr[kb], Bh[kb], acc0, 0, 0, 0);
    }

    // ---- cross-kh reduce, gates, state update ----
    float aT[16];
#pragma unroll
    for (int i = 0; i < 16; ++i) aT[i] = acc0[i] + acc1[i];
    {
      int h2 = 1 - kh;
#pragma unroll
      for (int i = 0; i < 8; ++i)
        scr[ct * 1024 + h2 * 512 + i * 64 + lane] = aT[h2 * 8 + i];
    }
    __syncthreads();

    const bool lastT = (t == S_ - 1);
#pragma unroll
    for (int i = 0; i < 8; ++i) {
      int r = kh * 8 + i;
      float pre = aT[r] + scr[ct * 1024 + kh * 512 + i * 64 + lane] + bias;
      // gate 2 -> tanh (overflow-safe), others -> sigmoid
      float e = __expf((gate == 2) ? (2.f * pre) : (-pre));
      float act = (gate == 2) ? (1.f - 2.f / (e + 1.f)) : (1.f / (1.f + e));
      int qb = lane & ~3;   // quad holds f,i,g,o of one (row,unit)
      float F = __shfl(act, qb + 0, 64);
      float I = __shfl(act, qb + 1, 64);
      float G = __shfl(act, qb + 2, 64);
      float O = __shfl(act, qb + 3, 64);
      float cn = fmaf(F, c[i], I * G);
      c[i] = cn;
      float e2 = __expf(2.f * cn);
      float hv = O * (1.f - 2.f / (e2 + 1.f));
      if (gate == 0) {
        int rowL = (r & 3) + ((r >> 2) << 3) + (kgsel << 2);   // 0..31
        hstage[rowL * 16 + unitL] = f2bf(hv);
        if (lastT) {
          int grow = rq * 32 + rowL;
          int gunit = cg * 16 + unitL;
          out[65536 + grow * H_ + gunit] = hv;    // h output (fp32)
          out[196608 + grow * H_ + gunit] = cn;   // c output (fp32)
        }
      }
    }
    __syncthreads();

    // ---- publish: wave0 only. rot: fire-and-forget (self-validating data
    // is the flag; ack drains under next x-phase). non-rot: old ack+flag. ----
    if (tid < 64) {
      int row = tid >> 1, u16sel = tid & 1;
      uint4 v = ((const uint4*)hstage)[tid];
      uc_st16((u16*)(HA4 + tn + rq * 4096 + (size_t)(2 * cg + u16sel) * 32 + row), v);
      if (!rot) {
        asm volatile("s_waitcnt vmcnt(0)" ::: "memory");
        if (tid == 0)
          atomicAdd(&barrier[rq * 64], 1u);
      }
    }
  }

  // ---- epilogue: out = h_final @ Why^T + b ----
  if (!rot) {
    if (tid < 4) {
      u32 spins = 0;
      while (__hip_atomic_load(&barrier[tid * 64], __ATOMIC_RELAXED,
                               __HIP_MEMORY_SCOPE_AGENT) < 64u * (u32)S_) {
        __builtin_amdgcn_s_sleep(2);
        if (++spins > (1u << 22)) break;
      }
    }
    __syncthreads();
  }

  if (blockIdx.x < 32) {
    const int wg = blockIdx.x;
    const uint4* HF = HA4 + (rot ? (size_t)S_ * 16384 : 0);
    const int l15 = lane & 15;
    const int l4 = lane >> 4;
    const int colO = (wg << 4) + l15;
    v4f o0, o1;
#pragma unroll
    for (int i = 0; i < 4; ++i) { o0[i] = 0.f; o1[i] = 0.f; }
#pragma unroll 1
    for (int kc = 0; kc < 32; ++kc) {
      v8s bfrag = *(const v8s*)(WhyT + (size_t)colO * H_ + kc * 32 + (l4 << 3));
      size_t i0 = (size_t)w * 4096 + kc * 128 + l4 * 32 + l15;
      v8s a0, a1;
      if (rot) {
        // validity-retry on the step-256 buffer (replaces the final barrier)
        v4u A0, A1;
        u32 spins = 0;
        for (;;) {
          asm volatile("global_load_dwordx4 %0, %1, off sc0 sc1"
                       : "=v"(A0) : "v"((const u16*)(HF + i0)) : "memory");
          asm volatile("global_load_dwordx4 %0, %1, off sc0 sc1"
                       : "=v"(A1) : "v"((const u16*)(HF + i0 + 16)) : "memory");
          asm volatile("s_waitcnt vmcnt(0)" ::: "memory");
          __builtin_amdgcn_sched_barrier(0);
          int ok = (A0.x != 0u) & (A0.y != 0u) & (A0.z != 0u) & (A0.w != 0u) &
                   (A1.x != 0u) & (A1.y != 0u) & (A1.z != 0u) & (A1.w != 0u);
          if (__all(ok) || ++spins > (1u << 20)) break;
          __builtin_amdgcn_s_sleep(1);
        }
        a0 = __builtin_bit_cast(v8s, A0);
        a1 = __builtin_bit_cast(v8s, A1);
      } else {
        a0 = __builtin_bit_cast(v8s, uc_ld16((const u16*)(HF + i0)));
        a1 = __builtin_bit_cast(v8s, uc_ld16((const u16*)(HF + i0 + 16)));
      }
      o0 = __builtin_amdgcn_mfma_f32_16x16x32_bf16(a0, bfrag, o0, 0, 0, 0);
      o1 = __builtin_amdgcn_mfma_f32_16x16x32_bf16(a1, bfrag, o1, 0, 0, 0);
    }
    float bO = WhyB[colO];
#pragma unroll
    for (int r2 = 0; r2 < 4; ++r2) {
      int row = (w << 5) + (l4 << 2) + r2;
      out[row * O_ + colO] = o0[r2] + bO;
      out[(row + 16) * O_ + colO] = o1[r2] + bO;
    }
  }
}

// ------------------------------------------------------------- launch ----
extern "C" void kernel_launch(void* const* d_in, const int* in_sizes, int n_in,
                              void* d_out, int out_size, void* d_ws, size_t ws_size,
                              hipStream_t stream) {
  const float* x    = (const float*)d_in[0];
  const float* Wxf  = (const float*)d_in[1];
  const float* bf_  = (const float*)d_in[2];
  const float* Whf  = (const float*)d_in[3];
  const float* Wxi  = (const float*)d_in[4];
  const float* bi_  = (const float*)d_in[5];
  const float* Whi  = (const float*)d_in[6];
  const float* Wxg  = (const float*)d_in[7];
  const float* bg_  = (const float*)d_in[8];
  const float* Whg  = (const float*)d_in[9];
  const float* Wxo  = (const float*)d_in[10];
  const float* bo_  = (const float*)d_in[11];
  const float* Who  = (const float*)d_in[12];
  const float* Why  = (const float*)d_in[13];
  const float* Whyb = (const float*)d_in[14];

  char* ws = (char*)d_ws;
  u16*   xtp  = (u16*)(ws);                    // xA: 33,554,432 B
  u16*   Wcp  = (u16*)(ws + 33554432);         // WcF: 12,582,912 B
  float* bcp  = (float*)(ws + 46137344);       //     16,384 B
  u16*   WhyT = (u16*)(ws + 46153728);         //  1,048,576 B
  u32*   barp = (u32*)(ws + 47202304);         //      1,024 B (4 padded counters)
  u16*   hbuf = (u16*)(ws + 47203328);         // hA: rot 257*256KB else 512KB
  float* outp = (float*)d_out;

  const size_t need_rot = 47203328ull + 257ull * 262144ull;  // ~114.6 MB
  int rot = (ws_size >= need_rot) ? 1 : 0;

  lstm_prep<<<dim3(1024), dim3(256), 0, stream>>>(
      x, Whf, Whi, Whg, Who, Wxf, Wxi, Wxg, Wxo,
      bf_, bi_, bg_, bo_, Why, xtp, Wcp, bcp, WhyT, hbuf, barp, rot);

  lstm_seq<<<dim3(256), dim3(256), 0, stream>>>(
      xtp, Wcp, bcp, hbuf, WhyT, Whyb, outp, barp, rot);
}

// Round 7
// 2458.272 us; speedup vs baseline: 1.0059x; 1.0059x over previous
//
#include <hip/hip_runtime.h>

// LSTM: B=128, S=256, I=512, H=1024, O=512.
// R15 = hybrid of R13 (cached bulk fetch) and R14 (flagless sentinel):
//  (1) Producer publish fire-and-forget (no vmcnt, no flag). Ack is hidden:
//      wave0's next x-phase loads are younger in the vmcnt FIFO, so the
//      compiler's own vmcnt(K<16) before x-MFMA drains the stores.
//  (2) Gate: vmcnt(0)+__syncthreads before the h-burst. Wave0's arrival
//      certifies its own publish landed -- local timing proxy for peers'
//      lockstep publishes (replaces the flag-detect RT).
//  (3) Consumer round-1 burst = PLAIN CACHED loads (coalesced line fills,
//      R13's fast path), sentinel-validated (0x0000 = unwritten; f2bf maps
//      +0 -> 0x0001 = 1e-38). Only invalid frags retry via UC (sc0 sc1)
//      loads, paced with s_sleep(1). Stale L2 fills (peer write-through does
//      NOT invalidate other XCDs' L2) are caught by validation and healed by
//      the UC retry -- correct under any arrival order; the one-time start
//      acquire fence handles cross-replay staleness as before.
//  Chain per step: act -> store one-way to LLC (overlapped with consumer's
//  own x+barrier) -> cached fetch (1 RT) -> MFMA. R13 had 3 serial RTs
//  (publish-ack, flag-detect, fetch); R15 keeps only the fetch.
// 256 blocks x 256 thr: block = (rq = blockIdx>>6: rows rq*32..+31,
// cg = blockIdx&63: gate-cols cg*64..+63). Wave (ct = w&1, kh = w>>1).
// Non-rot fallback keeps the R13 flag protocol.

#define B_ 128
#define S_ 256
#define I_ 512
#define H_ 1024
#define O_ 512

typedef unsigned short u16;
typedef unsigned int u32;
typedef unsigned long long u64;

typedef short v8s __attribute__((ext_vector_type(8)));
typedef unsigned int v4u __attribute__((ext_vector_type(4)));
typedef float v16f __attribute__((ext_vector_type(16)));
typedef float v4f __attribute__((ext_vector_type(4)));

__device__ __forceinline__ u16 f2bf(float f) {
  u32 u = __float_as_uint(f);
  u32 r = (u + 0x7fffu + ((u >> 16) & 1u)) >> 16;   // RNE
  r += (r == 0u);   // reserve 0x0000 as "not written"; +0 -> 0x0001 (1e-38)
  return (u16)r;
}
__device__ __forceinline__ u32 pack2(float a, float b) {
  return (u32)f2bf(a) | ((u32)f2bf(b) << 16);
}
__device__ __forceinline__ uint4 cvt8(const float* __restrict__ s) {
  float4 f0 = ((const float4*)s)[0];
  float4 f1 = ((const float4*)s)[1];
  uint4 o;
  o.x = pack2(f0.x, f0.y); o.y = pack2(f0.z, f0.w);
  o.z = pack2(f1.x, f1.y); o.w = pack2(f1.z, f1.w);
  return o;
}

__device__ __forceinline__ uint4 uc_ld16(const u16* p) {
  u64 lo = __hip_atomic_load((const u64*)p, __ATOMIC_RELAXED, __HIP_MEMORY_SCOPE_AGENT);
  u64 hi = __hip_atomic_load((const u64*)p + 1, __ATOMIC_RELAXED, __HIP_MEMORY_SCOPE_AGENT);
  uint4 v; v.x = (u32)lo; v.y = (u32)(lo >> 32); v.z = (u32)hi; v.w = (u32)(hi >> 32);
  return v;
}
// Agent-visible 16B publish store: plain dwordx4, write-through (sc0 sc1).
__device__ __forceinline__ void uc_st16(u16* p, uint4 v) {
  v4u d;
  d.x = v.x; d.y = v.y; d.z = v.z; d.w = v.w;
  asm volatile("global_store_dwordx4 %0, %1, off sc0 sc1"
               :: "v"(p), "v"(d) : "memory");
}

// ---------------------------------------------------------------- prep ----
__global__ void lstm_prep(
    const float* __restrict__ x,
    const float* __restrict__ Whf, const float* __restrict__ Whi,
    const float* __restrict__ Whg, const float* __restrict__ Who,
    const float* __restrict__ Wxf, const float* __restrict__ Wxi,
    const float* __restrict__ Wxg, const float* __restrict__ Wxo,
    const float* __restrict__ bfp, const float* __restrict__ bip,
    const float* __restrict__ bgp, const float* __restrict__ bop,
    const float* __restrict__ Why,
    u16* __restrict__ xt, u16* __restrict__ Wc, float* __restrict__ bc,
    u16* __restrict__ WhyT, u16* __restrict__ hbuf, u32* __restrict__ barrier,
    int rotFlag)
{
  const int gid = blockIdx.x * blockDim.x + threadIdx.x;
  const int gsz = gridDim.x * blockDim.x;

  if (gid < 256) barrier[gid] = 0u;

  // xA[t][rq][w8 0..63][row 0..31] (16B units) <- x[b=rq*32+row][t][w8*8..+8]
  for (int v = gid; v < (S_ * B_ * I_ / 8); v += gsz) {
    int flat = v * 8;
    int b = flat / (S_ * I_);
    int rem = flat - b * (S_ * I_);
    int t = rem / I_;
    int i = rem - t * I_;
    size_t dst = ((size_t)(t * 4 + (b >> 5)) * 64 + (i >> 3)) * 32 + (b & 31);
    ((uint4*)xt)[dst] = cvt8(x + flat);
  }

  // WcF[w8 0..191][colG 0..4095]: w8<64 -> Wx k=w8*8 ; w8>=64 -> Wh k=(w8-64)*8
  for (int o = gid; o < 192 * 4096; o += gsz) {
    int w8 = o >> 12;
    int colG = o & 4095;
    int unit = ((colG >> 6) << 4) + (((colG >> 5) & 1) << 3) + ((colG >> 2) & 7);
    int g = colG & 3;
    const float* Whp = (g == 0) ? Whf : (g == 1) ? Whi : (g == 2) ? Whg : Who;
    const float* Wxp = (g == 0) ? Wxf : (g == 1) ? Wxi : (g == 2) ? Wxg : Wxo;
    const float* s = (w8 < 64) ? (Wxp + (size_t)unit * 512 + w8 * 8)
                               : (Whp + (size_t)unit * 1024 + (w8 - 64) * 8);
    ((uint4*)Wc)[o] = cvt8(s);
  }

  // bias (colG-indexed)
  for (int n = gid; n < 4096; n += gsz) {
    int unit = ((n >> 6) << 4) + (((n >> 5) & 1) << 3) + ((n >> 2) & 7);
    int g = n & 3;
    const float* bp = (g == 0) ? bfp : (g == 1) ? bip : (g == 2) ? bgp : bop;
    bc[n] = bp[unit];
  }

  // Why -> bf16 (row-major [o][k])
  for (int v = gid; v < (O_ * H_ / 8); v += gsz) {
    int flat = v * 8;
    *(uint4*)(WhyT + flat) = cvt8(Why + flat);
  }

  // rot: buffer0 = encoded zeros (0x0001 bf16, h_0 ~= 0), buffers 1..256 = 0
  // ("not yet written"). non-rot: plain-zero hA[0], hA[1] (old flag path).
  if (rotFlag) {
    for (int v = gid; v < 257 * 16384; v += gsz) {
      u32 wv = (v < 16384) ? 0x00010001u : 0u;
      uint4 z; z.x = wv; z.y = wv; z.z = wv; z.w = wv;
      ((uint4*)hbuf)[v] = z;
    }
  } else {
    for (int v = gid; v < 2 * 16384; v += gsz) {
      uint4 z; z.x = 0; z.y = 0; z.z = 0; z.w = 0;
      ((uint4*)hbuf)[v] = z;
    }
  }
}

// ------------------------------------------------------ persistent LSTM ----
__global__ __launch_bounds__(256, 1) void lstm_seq(
    const u16* __restrict__ xt, const u16* __restrict__ Wc,
    const float* __restrict__ bc, u16* __restrict__ hbuf,
    const u16* __restrict__ WhyT, const float* __restrict__ WhyB,
    float* __restrict__ out, u32* __restrict__ barrier, int rotFlag)
{
  __shared__ float scr[2048];   // cross-kh partial-sum exchange (8 KB)
  __shared__ u16 hstage[512];   // h gather tile: [row 0..31][unitL 0..15]

  const int tid  = threadIdx.x;
  const int lane = tid & 63;
  const int w    = tid >> 6;
  const int ct   = w & 1;             // col tile (32 cols)
  const int kh   = w >> 1;            // K half
  const int rq   = blockIdx.x >> 6;   // rows rq*32..+31
  const int cg   = blockIdx.x & 63;   // gate-cols cg*64..+63
  const bool rot = (rotFlag != 0);

  const int colN  = lane & 31;
  const int kgsel = lane >> 5;
  const int colG  = cg * 64 + ct * 32 + colN;
  const int gate  = colN & 3;                 // 0=f 1=i 2=g 3=o
  const int unitL = ct * 8 + (colN >> 2);
  const float bias = bc[colG];

  const uint4* xA4  = (const uint4*)xt;
  const uint4* WcF4 = (const uint4*)Wc;
  uint4*       HA4  = (uint4*)hbuf;

  const int xaOff = rq * 2048 + kh * 1024 + lane;                 // + t*8192 + kb*64
  const int xbOff = kh * 131072 + kgsel * 4096 + colG;            // + kb*8192
  const int haOff = rq * 4096 + kh * 2048 + lane;                 // + tb + kb*64
  const int hbOff = 262144 + kh * 262144 + kgsel * 4096 + colG;   // + kb*8192

  float c[8];
#pragma unroll
  for (int i = 0; i < 8; ++i) c[i] = 0.f;

  // One-time acquire: drop stale lines (incl. previous-replay h buffers) so
  // cached round-1 reads and the B preload are correct.
  __builtin_amdgcn_fence(__ATOMIC_ACQUIRE, "agent");
  __syncthreads();

  // ---- park ALL weight B-frags in registers (192 regs/lane, AV->AGPR) ----
  v8s Bx[16], Bh[32];
  {
    const uint4* bx = WcF4 + xbOff;
#pragma unroll
    for (int kb = 0; kb < 16; ++kb)
      Bx[kb] = __builtin_bit_cast(v8s, bx[(size_t)kb * 8192]);
    const uint4* bh = WcF4 + hbOff;
#pragma unroll
    for (int kb = 0; kb < 32; ++kb)
      Bh[kb] = __builtin_bit_cast(v8s, bh[(size_t)kb * 8192]);
  }

  v16f acc0, acc1;

#pragma unroll 1
  for (int t = 0; t < S_; ++t) {
    const size_t tb = rot ? (size_t)t * 16384 : (size_t)(t & 1) * 16384;
    const size_t tn = rot ? (size_t)(t + 1) * 16384 : (size_t)((t & 1) ^ 1) * 16384;

#pragma unroll
    for (int i = 0; i < 16; ++i) { acc0[i] = 0.f; acc1[i] = 0.f; }

    // ---- x-phase: burst-load 16 A-frags, then MFMA against parked Bx ----
    // (wave0's publish stores of t-1 are older in the vmcnt FIFO; the
    // compiler's waits before these MFMAs drain them -- free ack.)
    {
      const uint4* ax = xA4 + (size_t)t * 8192 + xaOff;
      v8s xr[16];
#pragma unroll
      for (int kb = 0; kb < 16; ++kb)
        xr[kb] = __builtin_bit_cast(v8s, ax[kb * 64]);
#pragma unroll
      for (int kb = 0; kb < 16; ++kb) {
        if (kb & 1) acc1 = __builtin_amdgcn_mfma_f32_32x32x16_bf16(xr[kb], Bx[kb], acc1, 0, 0, 0);
        else        acc0 = __builtin_amdgcn_mfma_f32_32x32x16_bf16(xr[kb], Bx[kb], acc0, 0, 0, 0);
      }
    }

    // ---- h-phase ----
    v8s hr[32];
    if (rot) {
      // Gate: wave0 arrival at this barrier certifies its t-1 publish landed
      // (local proxy for peers' lockstep publishes). Then round-1 CACHED
      // burst + sentinel validation; UC paced retry only for invalid frags.
      asm volatile("s_waitcnt vmcnt(0)" ::: "memory");
      __syncthreads();
      const uint4* ah = HA4 + tb + haOff;
      v4u t0[32];
#pragma unroll
      for (int kb = 0; kb < 32; ++kb)
        t0[kb] = __builtin_bit_cast(v4u, ah[kb * 64]);
      u32 need = 0xffffffffu;
      u32 spins = 0;
      for (;;) {
#pragma unroll
        for (int kb = 0; kb < 32; ++kb)
          if ((need >> kb) & 1u) {
            int ok = (t0[kb].x != 0u) & (t0[kb].y != 0u) &
                     (t0[kb].z != 0u) & (t0[kb].w != 0u);
            if (__all(ok)) need &= ~(1u << kb);
          }
        if (!need || ++spins > (1u << 20)) break;
        __builtin_amdgcn_s_sleep(1);   // pace retry rounds (LLC congestion)
#pragma unroll
        for (int kb = 0; kb < 32; ++kb)
          if ((need >> kb) & 1u)
            asm volatile("global_load_dwordx4 %0, %1, off sc0 sc1"
                         : "=v"(t0[kb]) : "v"((const u16*)(ah + kb * 64)) : "memory");
        asm volatile("s_waitcnt vmcnt(0)" ::: "memory");
        __builtin_amdgcn_sched_barrier(0);
      }
#pragma unroll
      for (int kb = 0; kb < 32; ++kb)
        hr[kb] = __builtin_bit_cast(v8s, t0[kb]);
    } else {
      // fallback: old flag wait + UC loads
      if (t > 0) {
        if (tid == 0) {
          u32 spins = 0;
          while (__hip_atomic_load(&barrier[rq * 64], __ATOMIC_RELAXED,
                                   __HIP_MEMORY_SCOPE_AGENT) < 64u * (u32)t) {
            __builtin_amdgcn_s_sleep(1);
            if (++spins > (1u << 22)) break;
          }
        }
        __syncthreads();
      }
      const uint4* ah = HA4 + tb + haOff;
#pragma unroll
      for (int kb = 0; kb < 32; ++kb)
        hr[kb] = __builtin_bit_cast(v8s, uc_ld16((const u16*)(ah + kb * 64)));
    }

#pragma unroll
    for (int kb = 0; kb < 32; ++kb) {
      if (kb & 1) acc1 = __builtin_amdgcn_mfma_f32_32x32x16_bf16(hr[kb], Bh[kb], acc1, 0, 0, 0);
      else        acc0 = __builtin_amdgcn_mfma_f32_32x32x16_bf16(hr[kb], Bh[kb], acc0, 0, 0, 0);
    }

    // ---- cross-kh reduce, gates, state update ----
    float aT[16];
#pragma unroll
    for (int i = 0; i < 16; ++i) aT[i] = acc0[i] + acc1[i];
    {
      int h2 = 1 - kh;
#pragma unroll
      for (int i = 0; i < 8; ++i)
        scr[ct * 1024 + h2 * 512 + i * 64 + lane] = aT[h2 * 8 + i];
    }
    __syncthreads();

    const bool lastT = (t == S_ - 1);
#pragma unroll
    for (int i = 0; i < 8; ++i) {
      int r = kh * 8 + i;
      float pre = aT[r] + scr[ct * 1024 + kh * 512 + i * 64 + lane] + bias;
      // gate 2 -> tanh (overflow-safe), others -> sigmoid
      float e = __expf((gate == 2) ? (2.f * pre) : (-pre));
      float act = (gate == 2) ? (1.f - 2.f / (e + 1.f)) : (1.f / (1.f + e));
      int qb = lane & ~3;   // quad holds f,i,g,o of one (row,unit)
      float F = __shfl(act, qb + 0, 64);
      float I = __shfl(act, qb + 1, 64);
      float G = __shfl(act, qb + 2, 64);
      float O = __shfl(act, qb + 3, 64);
      float cn = fmaf(F, c[i], I * G);
      c[i] = cn;
      float e2 = __expf(2.f * cn);
      float hv = O * (1.f - 2.f / (e2 + 1.f));
      if (gate == 0) {
        int rowL = (r & 3) + ((r >> 2) << 3) + (kgsel << 2);   // 0..31
        hstage[rowL * 16 + unitL] = f2bf(hv);
        if (lastT) {
          int grow = rq * 32 + rowL;
          int gunit = cg * 16 + unitL;
          out[65536 + grow * H_ + gunit] = hv;    // h output (fp32)
          out[196608 + grow * H_ + gunit] = cn;   // c output (fp32)
        }
      }
    }
    __syncthreads();

    // ---- publish: wave0 only. rot: fire-and-forget (sentinel data is the
    // flag; ack drains under next x-phase). non-rot: old ack+flag. ----
    if (tid < 64) {
      int row = tid >> 1, u16sel = tid & 1;
      uint4 v = ((const uint4*)hstage)[tid];
      uc_st16((u16*)(HA4 + tn + rq * 4096 + (size_t)(2 * cg + u16sel) * 32 + row), v);
      if (!rot) {
        asm volatile("s_waitcnt vmcnt(0)" ::: "memory");
        if (tid == 0)
          atomicAdd(&barrier[rq * 64], 1u);
      }
    }
  }

  // ---- epilogue: out = h_final @ Why^T + b ----
  if (!rot) {
    if (tid < 4) {
      u32 spins = 0;
      while (__hip_atomic_load(&barrier[tid * 64], __ATOMIC_RELAXED,
                               __HIP_MEMORY_SCOPE_AGENT) < 64u * (u32)S_) {
        __builtin_amdgcn_s_sleep(2);
        if (++spins > (1u << 22)) break;
      }
    }
    __syncthreads();
  }

  if (blockIdx.x < 32) {
    const int wg = blockIdx.x;
    const uint4* HF = HA4 + (rot ? (size_t)S_ * 16384 : 0);
    const int l15 = lane & 15;
    const int l4 = lane >> 4;
    const int colO = (wg << 4) + l15;
    v4f o0, o1;
#pragma unroll
    for (int i = 0; i < 4; ++i) { o0[i] = 0.f; o1[i] = 0.f; }
#pragma unroll 1
    for (int kc = 0; kc < 32; ++kc) {
      v8s bfrag = *(const v8s*)(WhyT + (size_t)colO * H_ + kc * 32 + (l4 << 3));
      size_t i0 = (size_t)w * 4096 + kc * 128 + l4 * 32 + l15;
      v8s a0, a1;
      if (rot) {
        // validity-retry on the step-256 buffer (replaces the final barrier)
        v4u A0, A1;
        u32 spins = 0;
        for (;;) {
          asm volatile("global_load_dwordx4 %0, %1, off sc0 sc1"
                       : "=v"(A0) : "v"((const u16*)(HF + i0)) : "memory");
          asm volatile("global_load_dwordx4 %0, %1, off sc0 sc1"
                       : "=v"(A1) : "v"((const u16*)(HF + i0 + 16)) : "memory");
          asm volatile("s_waitcnt vmcnt(0)" ::: "memory");
          __builtin_amdgcn_sched_barrier(0);
          int ok = (A0.x != 0u) & (A0.y != 0u) & (A0.z != 0u) & (A0.w != 0u) &
                   (A1.x != 0u) & (A1.y != 0u) & (A1.z != 0u) & (A1.w != 0u);
          if (__all(ok) || ++spins > (1u << 20)) break;
          __builtin_amdgcn_s_sleep(1);
        }
        a0 = __builtin_bit_cast(v8s, A0);
        a1 = __builtin_bit_cast(v8s, A1);
      } else {
        a0 = __builtin_bit_cast(v8s, uc_ld16((const u16*)(HF + i0)));
        a1 = __builtin_bit_cast(v8s, uc_ld16((const u16*)(HF + i0 + 16)));
      }
      o0 = __builtin_amdgcn_mfma_f32_16x16x32_bf16(a0, bfrag, o0, 0, 0, 0);
      o1 = __builtin_amdgcn_mfma_f32_16x16x32_bf16(a1, bfrag, o1, 0, 0, 0);
    }
    float bO = WhyB[colO];
#pragma unroll
    for (int r2 = 0; r2 < 4; ++r2) {
      int row = (w << 5) + (l4 << 2) + r2;
      out[row * O_ + colO] = o0[r2] + bO;
      out[(row + 16) * O_ + colO] = o1[r2] + bO;
    }
  }
}

// ------------------------------------------------------------- launch ----
extern "C" void kernel_launch(void* const* d_in, const int* in_sizes, int n_in,
                              void* d_out, int out_size, void* d_ws, size_t ws_size,
                              hipStream_t stream) {
  const float* x    = (const float*)d_in[0];
  const float* Wxf  = (const float*)d_in[1];
  const float* bf_  = (const float*)d_in[2];
  const float* Whf  = (const float*)d_in[3];
  const float* Wxi  = (const float*)d_in[4];
  const float* bi_  = (const float*)d_in[5];
  const float* Whi  = (const float*)d_in[6];
  const float* Wxg  = (const float*)d_in[7];
  const float* bg_  = (const float*)d_in[8];
  const float* Whg  = (const float*)d_in[9];
  const float* Wxo  = (const float*)d_in[10];
  const float* bo_  = (const float*)d_in[11];
  const float* Who  = (const float*)d_in[12];
  const float* Why  = (const float*)d_in[13];
  const float* Whyb = (const float*)d_in[14];

  char* ws = (char*)d_ws;
  u16*   xtp  = (u16*)(ws);                    // xA: 33,554,432 B
  u16*   Wcp  = (u16*)(ws + 33554432);         // WcF: 12,582,912 B
  float* bcp  = (float*)(ws + 46137344);       //     16,384 B
  u16*   WhyT = (u16*)(ws + 46153728);         //  1,048,576 B
  u32*   barp = (u32*)(ws + 47202304);         //      1,024 B (4 padded counters)
  u16*   hbuf = (u16*)(ws + 47203328);         // hA: rot 257*256KB else 512KB
  float* outp = (float*)d_out;

  const size_t need_rot = 47203328ull + 257ull * 262144ull;  // ~114.6 MB
  int rot = (ws_size >= need_rot) ? 1 : 0;

  lstm_prep<<<dim3(1024), dim3(256), 0, stream>>>(
      x, Whf, Whi, Whg, Who, Wxf, Wxi, Wxg, Wxo,
      bf_, bi_, bg_, bo_, Why, xtp, Wcp, bcp, WhyT, hbuf, barp, rot);

  lstm_seq<<<dim3(256), dim3(256), 0, stream>>>(
      xtp, Wcp, bcp, hbuf, WhyT, Whyb, outp, barp, rot);
}

// Round 8
// 2051.916 us; speedup vs baseline: 1.2050x; 1.1980x over previous
//
#include <hip/hip_runtime.h>

// LSTM: B=128, S=256, I=512, H=1024, O=512.
// R16 = R13 EXACTLY (flag protocol: wave0-solo publish via coalesced sc0/sc1
// stores, vmcnt(0) ack, per-rq aggregated counter, single-lane poll, cached
// h fetch in rot mode) + ONE change:
//  XCD-LOCAL CLIQUE PLACEMENT: blockIdx%8 maps to XCD on MI355X (measured
//  heuristic). Old decode rq=blockIdx>>6 scattered each 64-block rq-clique
//  across all 8 XCDs -> every h-fetch leg was an LLC round trip. New decode
//  rq=(blockIdx&7)>>1, cg=(blockIdx>>3)*2+(blockIdx&1) puts each clique on
//  an XCD PAIR {2rq,2rq+1} (1 block/CU x 32 CUs x 2). Publish stores are
//  write-through (sc0 sc1): they update the producer's local L2 AND LLC, so
//  ~50% of a consumer's h-frags (same-XCD producers) become local L2 hits
//  (~200cy) instead of LLC trips. Flag + cross-XCD frags unchanged (LLC).
//  Pure placement heuristic: if %8 ever changes, protocol is still R13's ->
//  correct, just not faster.
// 256 blocks x 256 thr. Wave (ct = w&1, kh = w>>1).

#define B_ 128
#define S_ 256
#define I_ 512
#define H_ 1024
#define O_ 512

typedef unsigned short u16;
typedef unsigned int u32;
typedef unsigned long long u64;

typedef short v8s __attribute__((ext_vector_type(8)));
typedef unsigned int v4u __attribute__((ext_vector_type(4)));
typedef float v16f __attribute__((ext_vector_type(16)));
typedef float v4f __attribute__((ext_vector_type(4)));

__device__ __forceinline__ u16 f2bf(float f) {
  u32 u = __float_as_uint(f);
  u32 r = (u + 0x7fffu + ((u >> 16) & 1u)) >> 16;   // RNE
  return (u16)r;
}
__device__ __forceinline__ u32 pack2(float a, float b) {
  return (u32)f2bf(a) | ((u32)f2bf(b) << 16);
}
__device__ __forceinline__ uint4 cvt8(const float* __restrict__ s) {
  float4 f0 = ((const float4*)s)[0];
  float4 f1 = ((const float4*)s)[1];
  uint4 o;
  o.x = pack2(f0.x, f0.y); o.y = pack2(f0.z, f0.w);
  o.z = pack2(f1.x, f1.y); o.w = pack2(f1.z, f1.w);
  return o;
}

__device__ __forceinline__ uint4 uc_ld16(const u16* p) {
  u64 lo = __hip_atomic_load((const u64*)p, __ATOMIC_RELAXED, __HIP_MEMORY_SCOPE_AGENT);
  u64 hi = __hip_atomic_load((const u64*)p + 1, __ATOMIC_RELAXED, __HIP_MEMORY_SCOPE_AGENT);
  uint4 v; v.x = (u32)lo; v.y = (u32)(lo >> 32); v.z = (u32)hi; v.w = (u32)(hi >> 32);
  return v;
}
// Agent-visible 16B publish store: plain dwordx4, write-through (sc0 sc1).
// Coalesces across lanes; updates local L2 + LLC. Ack via caller's vmcnt(0).
__device__ __forceinline__ void uc_st16(u16* p, uint4 v) {
  v4u d;
  d.x = v.x; d.y = v.y; d.z = v.z; d.w = v.w;
  asm volatile("global_store_dwordx4 %0, %1, off sc0 sc1"
               :: "v"(p), "v"(d) : "memory");
}

// ---------------------------------------------------------------- prep ----
__global__ void lstm_prep(
    const float* __restrict__ x,
    const float* __restrict__ Whf, const float* __restrict__ Whi,
    const float* __restrict__ Whg, const float* __restrict__ Who,
    const float* __restrict__ Wxf, const float* __restrict__ Wxi,
    const float* __restrict__ Wxg, const float* __restrict__ Wxo,
    const float* __restrict__ bfp, const float* __restrict__ bip,
    const float* __restrict__ bgp, const float* __restrict__ bop,
    const float* __restrict__ Why,
    u16* __restrict__ xt, u16* __restrict__ Wc, float* __restrict__ bc,
    u16* __restrict__ WhyT, u16* __restrict__ hbuf, u32* __restrict__ barrier)
{
  const int gid = blockIdx.x * blockDim.x + threadIdx.x;
  const int gsz = gridDim.x * blockDim.x;

  if (gid < 256) barrier[gid] = 0u;

  // xA[t][rq][w8 0..63][row 0..31] (16B units) <- x[b=rq*32+row][t][w8*8..+8]
  for (int v = gid; v < (S_ * B_ * I_ / 8); v += gsz) {
    int flat = v * 8;
    int b = flat / (S_ * I_);
    int rem = flat - b * (S_ * I_);
    int t = rem / I_;
    int i = rem - t * I_;
    size_t dst = ((size_t)(t * 4 + (b >> 5)) * 64 + (i >> 3)) * 32 + (b & 31);
    ((uint4*)xt)[dst] = cvt8(x + flat);
  }

  // WcF[w8 0..191][colG 0..4095]: w8<64 -> Wx k=w8*8 ; w8>=64 -> Wh k=(w8-64)*8
  for (int o = gid; o < 192 * 4096; o += gsz) {
    int w8 = o >> 12;
    int colG = o & 4095;
    int unit = ((colG >> 6) << 4) + (((colG >> 5) & 1) << 3) + ((colG >> 2) & 7);
    int g = colG & 3;
    const float* Whp = (g == 0) ? Whf : (g == 1) ? Whi : (g == 2) ? Whg : Who;
    const float* Wxp = (g == 0) ? Wxf : (g == 1) ? Wxi : (g == 2) ? Wxg : Wxo;
    const float* s = (w8 < 64) ? (Wxp + (size_t)unit * 512 + w8 * 8)
                               : (Whp + (size_t)unit * 1024 + (w8 - 64) * 8);
    ((uint4*)Wc)[o] = cvt8(s);
  }

  // bias (colG-indexed)
  for (int n = gid; n < 4096; n += gsz) {
    int unit = ((n >> 6) << 4) + (((n >> 5) & 1) << 3) + ((n >> 2) & 7);
    int g = n & 3;
    const float* bp = (g == 0) ? bfp : (g == 1) ? bip : (g == 2) ? bgp : bop;
    bc[n] = bp[unit];
  }

  // Why -> bf16 (row-major [o][k])
  for (int v = gid; v < (O_ * H_ / 8); v += gsz) {
    int flat = v * 8;
    *(uint4*)(WhyT + flat) = cvt8(Why + flat);
  }

  // zero hA[0] and hA[1]
  for (int v = gid; v < 2 * 16384; v += gsz) {
    uint4 z; z.x = 0; z.y = 0; z.z = 0; z.w = 0;
    ((uint4*)hbuf)[v] = z;
  }
}

// ------------------------------------------------------ persistent LSTM ----
__global__ __launch_bounds__(256, 1) void lstm_seq(
    const u16* __restrict__ xt, const u16* __restrict__ Wc,
    const float* __restrict__ bc, u16* __restrict__ hbuf,
    const u16* __restrict__ WhyT, const float* __restrict__ WhyB,
    float* __restrict__ out, u32* __restrict__ barrier, int rotFlag)
{
  __shared__ float scr[2048];   // cross-kh partial-sum exchange (8 KB)
  __shared__ u16 hstage[512];   // h gather tile: [row 0..31][unitL 0..15]

  const int tid  = threadIdx.x;
  const int lane = tid & 63;
  const int w    = tid >> 6;
  const int ct   = w & 1;             // col tile (32 cols)
  const int kh   = w >> 1;            // K half
  // XCD-local clique decode: blockIdx%8 ~ XCD (MI355X heuristic). Clique rq
  // occupies XCD pair {2rq, 2rq+1}; cg parity = XCD within pair.
  const int rq   = (blockIdx.x & 7) >> 1;                      // rows rq*32..+31
  const int cg   = ((blockIdx.x >> 3) << 1) | (blockIdx.x & 1); // gate-cols cg*64..+63
  const bool rot = (rotFlag != 0);

  const int colN  = lane & 31;
  const int kgsel = lane >> 5;
  const int colG  = cg * 64 + ct * 32 + colN;
  const int gate  = colN & 3;                 // 0=f 1=i 2=g 3=o
  const int unitL = ct * 8 + (colN >> 2);
  const float bias = bc[colG];

  const uint4* xA4  = (const uint4*)xt;
  const uint4* WcF4 = (const uint4*)Wc;
  uint4*       HA4  = (uint4*)hbuf;

  const int xaOff = rq * 2048 + kh * 1024 + lane;                 // + t*8192 + kb*64
  const int xbOff = kh * 131072 + kgsel * 4096 + colG;            // + kb*8192
  const int haOff = rq * 4096 + kh * 2048 + lane;                 // + tb + kb*64
  const int hbOff = 262144 + kh * 262144 + kgsel * 4096 + colG;   // + kb*8192

  float c[8];
#pragma unroll
  for (int i = 0; i < 8; ++i) c[i] = 0.f;

  // One-time acquire: drop stale memset-poison / pre-prep lines so cached
  // reads of rotating h buffers (and the B preload) are correct.
  __builtin_amdgcn_fence(__ATOMIC_ACQUIRE, "agent");
  __syncthreads();

  // ---- park ALL weight B-frags in registers (192 regs/lane, AV->AGPR) ----
  v8s Bx[16], Bh[32];
  {
    const uint4* bx = WcF4 + xbOff;
#pragma unroll
    for (int kb = 0; kb < 16; ++kb)
      Bx[kb] = __builtin_bit_cast(v8s, bx[(size_t)kb * 8192]);
    const uint4* bh = WcF4 + hbOff;
#pragma unroll
    for (int kb = 0; kb < 32; ++kb)
      Bh[kb] = __builtin_bit_cast(v8s, bh[(size_t)kb * 8192]);
  }

  v16f acc0, acc1;

#pragma unroll 1
  for (int t = 0; t < S_; ++t) {
    const size_t tb = rot ? (size_t)t * 16384 : (size_t)(t & 1) * 16384;
    const size_t tn = rot ? (size_t)(t + 1) * 16384 : (size_t)((t & 1) ^ 1) * 16384;

#pragma unroll
    for (int i = 0; i < 16; ++i) { acc0[i] = 0.f; acc1[i] = 0.f; }

    // ---- x-phase: burst-load 16 A-frags, then MFMA against parked Bx ----
    {
      const uint4* ax = xA4 + (size_t)t * 8192 + xaOff;
      v8s xr[16];
#pragma unroll
      for (int kb = 0; kb < 16; ++kb)
        xr[kb] = __builtin_bit_cast(v8s, ax[kb * 64]);
#pragma unroll
      for (int kb = 0; kb < 16; ++kb) {
        if (kb & 1) acc1 = __builtin_amdgcn_mfma_f32_32x32x16_bf16(xr[kb], Bx[kb], acc1, 0, 0, 0);
        else        acc0 = __builtin_amdgcn_mfma_f32_32x32x16_bf16(xr[kb], Bx[kb], acc0, 0, 0, 0);
      }
    }

    // ---- rq-group wait: single-lane poll of the aggregated counter ----
    if (t > 0) {
      if (tid == 0) {
        u32 spins = 0;
        while (__hip_atomic_load(&barrier[rq * 64], __ATOMIC_RELAXED,
                                 __HIP_MEMORY_SCOPE_AGENT) < 64u * (u32)t) {
          __builtin_amdgcn_s_sleep(1);
          if (++spins > (1u << 22)) break;   // safety valve
        }
      }
      __syncthreads();
    }

    // ---- h-phase: burst-load 32 A-frags, MFMA against parked Bh ----
    // (rot: plain cached loads; ~50% of frags are same-XCD L2 hits under the
    // clique placement, rest fill from LLC.)
    {
      const uint4* ah = HA4 + tb + haOff;
      v8s hr[32];
      if (rot) {
#pragma unroll
        for (int kb = 0; kb < 32; ++kb)
          hr[kb] = __builtin_bit_cast(v8s, ah[kb * 64]);
      } else {
#pragma unroll
        for (int kb = 0; kb < 32; ++kb)
          hr[kb] = __builtin_bit_cast(v8s, uc_ld16((const u16*)(ah + kb * 64)));
      }
#pragma unroll
      for (int kb = 0; kb < 32; ++kb) {
        if (kb & 1) acc1 = __builtin_amdgcn_mfma_f32_32x32x16_bf16(hr[kb], Bh[kb], acc1, 0, 0, 0);
        else        acc0 = __builtin_amdgcn_mfma_f32_32x32x16_bf16(hr[kb], Bh[kb], acc0, 0, 0, 0);
      }
    }

    // ---- cross-kh reduce, gates, state update ----
    float aT[16];
#pragma unroll
    for (int i = 0; i < 16; ++i) aT[i] = acc0[i] + acc1[i];
    {
      int h2 = 1 - kh;
#pragma unroll
      for (int i = 0; i < 8; ++i)
        scr[ct * 1024 + h2 * 512 + i * 64 + lane] = aT[h2 * 8 + i];
    }
    __syncthreads();

    const bool lastT = (t == S_ - 1);
#pragma unroll
    for (int i = 0; i < 8; ++i) {
      int r = kh * 8 + i;
      float pre = aT[r] + scr[ct * 1024 + kh * 512 + i * 64 + lane] + bias;
      // gate 2 -> tanh (overflow-safe), others -> sigmoid
      float e = __expf((gate == 2) ? (2.f * pre) : (-pre));
      float act = (gate == 2) ? (1.f - 2.f / (e + 1.f)) : (1.f / (1.f + e));
      int qb = lane & ~3;   // quad holds f,i,g,o of one (row,unit)
      float F = __shfl(act, qb + 0, 64);
      float I = __shfl(act, qb + 1, 64);
      float G = __shfl(act, qb + 2, 64);
      float O = __shfl(act, qb + 3, 64);
      float cn = fmaf(F, c[i], I * G);
      c[i] = cn;
      float e2 = __expf(2.f * cn);
      float hv = O * (1.f - 2.f / (e2 + 1.f));
      if (gate == 0) {
        int rowL = (r & 3) + ((r >> 2) << 3) + (kgsel << 2);   // 0..31
        hstage[rowL * 16 + unitL] = f2bf(hv);
        if (lastT) {
          int grow = rq * 32 + rowL;
          int gunit = cg * 16 + unitL;
          out[65536 + grow * H_ + gunit] = hv;    // h output (fp32)
          out[196608 + grow * H_ + gunit] = cn;   // c output (fp32)
        }
      }
    }
    __syncthreads();

    // ---- publish: wave0 only (other waves run ahead to x of t+1; they
    // re-converge at the next wait's syncthreads, which also protects the
    // scr/hstage reuse ordering). Single atomicAdd advances the counter. ----
    if (tid < 64) {
      int row = tid >> 1, u16sel = tid & 1;
      uint4 v = ((const uint4*)hstage)[tid];
      uc_st16((u16*)(HA4 + tn + rq * 4096 + (size_t)(2 * cg + u16sel) * 32 + row), v);
      asm volatile("s_waitcnt vmcnt(0)" ::: "memory");
      if (tid == 0)
        atomicAdd(&barrier[rq * 64], 1u);
    }
  }

  // ---- full barrier (4 aggregated counters), then out = h @ Why^T + b ----
  {
    if (tid < 4) {
      u32 spins = 0;
      while (__hip_atomic_load(&barrier[tid * 64], __ATOMIC_RELAXED,
                               __HIP_MEMORY_SCOPE_AGENT) < 64u * (u32)S_) {
        __builtin_amdgcn_s_sleep(2);
        if (++spins > (1u << 22)) break;
      }
    }
  }
  __syncthreads();

  if (blockIdx.x < 32) {
    const int wg = blockIdx.x;
    const uint4* HF = HA4 + (rot ? (size_t)S_ * 16384 : 0);
    const int l15 = lane & 15;
    const int l4 = lane >> 4;
    const int colO = (wg << 4) + l15;
    v4f o0, o1;
#pragma unroll
    for (int i = 0; i < 4; ++i) { o0[i] = 0.f; o1[i] = 0.f; }
#pragma unroll 4
    for (int kc = 0; kc < 32; ++kc) {
      v8s bfrag = *(const v8s*)(WhyT + (size_t)colO * H_ + kc * 32 + (l4 << 3));
      size_t i0 = (size_t)w * 4096 + kc * 128 + l4 * 32 + l15;
      v8s a0, a1;
      if (rot) {
        a0 = __builtin_bit_cast(v8s, HF[i0]);
        a1 = __builtin_bit_cast(v8s, HF[i0 + 16]);
      } else {
        a0 = __builtin_bit_cast(v8s, uc_ld16((const u16*)(HF + i0)));
        a1 = __builtin_bit_cast(v8s, uc_ld16((const u16*)(HF + i0 + 16)));
      }
      o0 = __builtin_amdgcn_mfma_f32_16x16x32_bf16(a0, bfrag, o0, 0, 0, 0);
      o1 = __builtin_amdgcn_mfma_f32_16x16x32_bf16(a1, bfrag, o1, 0, 0, 0);
    }
    float bO = WhyB[colO];
#pragma unroll
    for (int r2 = 0; r2 < 4; ++r2) {
      int row = (w << 5) + (l4 << 2) + r2;
      out[row * O_ + colO] = o0[r2] + bO;
      out[(row + 16) * O_ + colO] = o1[r2] + bO;
    }
  }
}

// ------------------------------------------------------------- launch ----
extern "C" void kernel_launch(void* const* d_in, const int* in_sizes, int n_in,
                              void* d_out, int out_size, void* d_ws, size_t ws_size,
                              hipStream_t stream) {
  const float* x    = (const float*)d_in[0];
  const float* Wxf  = (const float*)d_in[1];
  const float* bf_  = (const float*)d_in[2];
  const float* Whf  = (const float*)d_in[3];
  const float* Wxi  = (const float*)d_in[4];
  const float* bi_  = (const float*)d_in[5];
  const float* Whi  = (const float*)d_in[6];
  const float* Wxg  = (const float*)d_in[7];
  const float* bg_  = (const float*)d_in[8];
  const float* Whg  = (const float*)d_in[9];
  const float* Wxo  = (const float*)d_in[10];
  const float* bo_  = (const float*)d_in[11];
  const float* Who  = (const float*)d_in[12];
  const float* Why  = (const float*)d_in[13];
  const float* Whyb = (const float*)d_in[14];

  char* ws = (char*)d_ws;
  u16*   xtp  = (u16*)(ws);                    // xA: 33,554,432 B
  u16*   Wcp  = (u16*)(ws + 33554432);         // WcF: 12,582,912 B
  float* bcp  = (float*)(ws + 46137344);       //     16,384 B
  u16*   WhyT = (u16*)(ws + 46153728);         //  1,048,576 B
  u32*   barp = (u32*)(ws + 47202304);         //      1,024 B (4 padded counters)
  u16*   hbuf = (u16*)(ws + 47203328);         // hA: rot 257*256KB else 512KB
  float* outp = (float*)d_out;

  const size_t need_rot = 47203328ull + 257ull * 262144ull;  // ~114.6 MB
  int rot = (ws_size >= need_rot) ? 1 : 0;

  lstm_prep<<<dim3(1024), dim3(256), 0, stream>>>(
      x, Whf, Whi, Whg, Who, Wxf, Wxi, Wxg, Wxo,
      bf_, bi_, bg_, bo_, Why, xtp, Wcp, bcp, WhyT, hbuf, barp);

  lstm_seq<<<dim3(256), dim3(256), 0, stream>>>(
      xtp, Wcp, bcp, hbuf, WhyT, Whyb, outp, barp, rot);
}

// Round 9
// 2015.133 us; speedup vs baseline: 1.2270x; 1.0183x over previous
//
#include <hip/hip_runtime.h>

// LSTM: B=128, S=256, I=512, H=1024, O=512.
// R17 = R16 (flag protocol + XCD-pair clique placement) + two leg cuts:
//  (1) PER-WAVE FLAG POLL: each wave's lane0 spins on the aggregated per-rq
//      counter; divergent-branch reconvergence gates the wave. Removes the
//      wait-side __syncthreads (barrier-wake of 3 parked waves) from the
//      detect->h-load path. Hazard audit: the post-act __syncthreads alone
//      orders scr/hstage reuse across steps (any wave's wait(t) exit implies
//      wave0's flag-add(t-1), which is after wave0's hstage(t-1) read).
//      2 syncthreads/step remain (reduce + post-act).
//  (2) COALESCED PREP: xt transpose iterates DST-major (consecutive threads
//      write consecutive 16B units); reads become 32B gathers that L2/LLC
//      absorb (x read ~once, 64MB). Old src-major version wrote at 512B
//      stride (uncoalesced) -- prep was ~98us of total.
// 256 blocks x 256 thr. Wave (ct = w&1, kh = w>>1). Clique rq on XCD pair
// {2rq,2rq+1} via rq=(blockIdx&7)>>1, cg=(blockIdx>>3)*2+(blockIdx&1).
// h: published via coalesced sc0/sc1 write-through stores (wave0-solo, ack
// via vmcnt(0), single atomicAdd per block), consumed CACHED from rotating
// per-step buffers. One-time acquire fence at start; no per-step fences.

#define B_ 128
#define S_ 256
#define I_ 512
#define H_ 1024
#define O_ 512

typedef unsigned short u16;
typedef unsigned int u32;
typedef unsigned long long u64;

typedef short v8s __attribute__((ext_vector_type(8)));
typedef unsigned int v4u __attribute__((ext_vector_type(4)));
typedef float v16f __attribute__((ext_vector_type(16)));
typedef float v4f __attribute__((ext_vector_type(4)));

__device__ __forceinline__ u16 f2bf(float f) {
  u32 u = __float_as_uint(f);
  u32 r = (u + 0x7fffu + ((u >> 16) & 1u)) >> 16;   // RNE
  return (u16)r;
}
__device__ __forceinline__ u32 pack2(float a, float b) {
  return (u32)f2bf(a) | ((u32)f2bf(b) << 16);
}
__device__ __forceinline__ uint4 cvt8(const float* __restrict__ s) {
  float4 f0 = ((const float4*)s)[0];
  float4 f1 = ((const float4*)s)[1];
  uint4 o;
  o.x = pack2(f0.x, f0.y); o.y = pack2(f0.z, f0.w);
  o.z = pack2(f1.x, f1.y); o.w = pack2(f1.z, f1.w);
  return o;
}

__device__ __forceinline__ uint4 uc_ld16(const u16* p) {
  u64 lo = __hip_atomic_load((const u64*)p, __ATOMIC_RELAXED, __HIP_MEMORY_SCOPE_AGENT);
  u64 hi = __hip_atomic_load((const u64*)p + 1, __ATOMIC_RELAXED, __HIP_MEMORY_SCOPE_AGENT);
  uint4 v; v.x = (u32)lo; v.y = (u32)(lo >> 32); v.z = (u32)hi; v.w = (u32)(hi >> 32);
  return v;
}
// Agent-visible 16B publish store: plain dwordx4, write-through (sc0 sc1).
// Coalesces across lanes; updates local L2 + LLC. Ack via caller's vmcnt(0).
__device__ __forceinline__ void uc_st16(u16* p, uint4 v) {
  v4u d;
  d.x = v.x; d.y = v.y; d.z = v.z; d.w = v.w;
  asm volatile("global_store_dwordx4 %0, %1, off sc0 sc1"
               :: "v"(p), "v"(d) : "memory");
}

// ---------------------------------------------------------------- prep ----
__global__ void lstm_prep(
    const float* __restrict__ x,
    const float* __restrict__ Whf, const float* __restrict__ Whi,
    const float* __restrict__ Whg, const float* __restrict__ Who,
    const float* __restrict__ Wxf, const float* __restrict__ Wxi,
    const float* __restrict__ Wxg, const float* __restrict__ Wxo,
    const float* __restrict__ bfp, const float* __restrict__ bip,
    const float* __restrict__ bgp, const float* __restrict__ bop,
    const float* __restrict__ Why,
    u16* __restrict__ xt, u16* __restrict__ Wc, float* __restrict__ bc,
    u16* __restrict__ WhyT, u16* __restrict__ hbuf, u32* __restrict__ barrier)
{
  const int gid = blockIdx.x * blockDim.x + threadIdx.x;
  const int gsz = gridDim.x * blockDim.x;

  if (gid < 256) barrier[gid] = 0u;

  // xA fill, DST-major (coalesced writes): unit v = ((t*4+rqb)*64+w8)*32+row
  // <- x[(rqb*32+row)*(S*I) + t*I + w8*8 .. +8]. Reads are 32B gathers.
  for (int v = gid; v < (S_ * B_ * I_ / 8); v += gsz) {
    int row = v & 31;
    int w8  = (v >> 5) & 63;
    int rqb = (v >> 11) & 3;
    int t   = v >> 13;
    int b   = rqb * 32 + row;
    size_t src = (size_t)b * (S_ * I_) + t * I_ + w8 * 8;
    ((uint4*)xt)[v] = cvt8(x + src);
  }

  // WcF[w8 0..191][colG 0..4095]: w8<64 -> Wx k=w8*8 ; w8>=64 -> Wh k=(w8-64)*8
  for (int o = gid; o < 192 * 4096; o += gsz) {
    int w8 = o >> 12;
    int colG = o & 4095;
    int unit = ((colG >> 6) << 4) + (((colG >> 5) & 1) << 3) + ((colG >> 2) & 7);
    int g = colG & 3;
    const float* Whp = (g == 0) ? Whf : (g == 1) ? Whi : (g == 2) ? Whg : Who;
    const float* Wxp = (g == 0) ? Wxf : (g == 1) ? Wxi : (g == 2) ? Wxg : Wxo;
    const float* s = (w8 < 64) ? (Wxp + (size_t)unit * 512 + w8 * 8)
                               : (Whp + (size_t)unit * 1024 + (w8 - 64) * 8);
    ((uint4*)Wc)[o] = cvt8(s);
  }

  // bias (colG-indexed)
  for (int n = gid; n < 4096; n += gsz) {
    int unit = ((n >> 6) << 4) + (((n >> 5) & 1) << 3) + ((n >> 2) & 7);
    int g = n & 3;
    const float* bp = (g == 0) ? bfp : (g == 1) ? bip : (g == 2) ? bgp : bop;
    bc[n] = bp[unit];
  }

  // Why -> bf16 (row-major [o][k])
  for (int v = gid; v < (O_ * H_ / 8); v += gsz) {
    int flat = v * 8;
    *(uint4*)(WhyT + flat) = cvt8(Why + flat);
  }

  // zero hA[0] and hA[1]
  for (int v = gid; v < 2 * 16384; v += gsz) {
    uint4 z; z.x = 0; z.y = 0; z.z = 0; z.w = 0;
    ((uint4*)hbuf)[v] = z;
  }
}

// ------------------------------------------------------ persistent LSTM ----
__global__ __launch_bounds__(256, 1) void lstm_seq(
    const u16* __restrict__ xt, const u16* __restrict__ Wc,
    const float* __restrict__ bc, u16* __restrict__ hbuf,
    const u16* __restrict__ WhyT, const float* __restrict__ WhyB,
    float* __restrict__ out, u32* __restrict__ barrier, int rotFlag)
{
  __shared__ float scr[2048];   // cross-kh partial-sum exchange (8 KB)
  __shared__ u16 hstage[512];   // h gather tile: [row 0..31][unitL 0..15]

  const int tid  = threadIdx.x;
  const int lane = tid & 63;
  const int w    = tid >> 6;
  const int ct   = w & 1;             // col tile (32 cols)
  const int kh   = w >> 1;            // K half
  // XCD-local clique decode: blockIdx%8 ~ XCD (MI355X heuristic). Clique rq
  // occupies XCD pair {2rq, 2rq+1}; cg parity = XCD within pair.
  const int rq   = (blockIdx.x & 7) >> 1;                      // rows rq*32..+31
  const int cg   = ((blockIdx.x >> 3) << 1) | (blockIdx.x & 1); // gate-cols cg*64..+63
  const bool rot = (rotFlag != 0);

  const int colN  = lane & 31;
  const int kgsel = lane >> 5;
  const int colG  = cg * 64 + ct * 32 + colN;
  const int gate  = colN & 3;                 // 0=f 1=i 2=g 3=o
  const int unitL = ct * 8 + (colN >> 2);
  const float bias = bc[colG];

  const uint4* xA4  = (const uint4*)xt;
  const uint4* WcF4 = (const uint4*)Wc;
  uint4*       HA4  = (uint4*)hbuf;

  const int xaOff = rq * 2048 + kh * 1024 + lane;                 // + t*8192 + kb*64
  const int xbOff = kh * 131072 + kgsel * 4096 + colG;            // + kb*8192
  const int haOff = rq * 4096 + kh * 2048 + lane;                 // + tb + kb*64
  const int hbOff = 262144 + kh * 262144 + kgsel * 4096 + colG;   // + kb*8192

  float c[8];
#pragma unroll
  for (int i = 0; i < 8; ++i) c[i] = 0.f;

  // One-time acquire: drop stale memset-poison / pre-prep lines so cached
  // reads of rotating h buffers (and the B preload) are correct.
  __builtin_amdgcn_fence(__ATOMIC_ACQUIRE, "agent");
  __syncthreads();

  // ---- park ALL weight B-frags in registers (192 regs/lane, AV->AGPR) ----
  v8s Bx[16], Bh[32];
  {
    const uint4* bx = WcF4 + xbOff;
#pragma unroll
    for (int kb = 0; kb < 16; ++kb)
      Bx[kb] = __builtin_bit_cast(v8s, bx[(size_t)kb * 8192]);
    const uint4* bh = WcF4 + hbOff;
#pragma unroll
    for (int kb = 0; kb < 32; ++kb)
      Bh[kb] = __builtin_bit_cast(v8s, bh[(size_t)kb * 8192]);
  }

  v16f acc0, acc1;

#pragma unroll 1
  for (int t = 0; t < S_; ++t) {
    const size_t tb = rot ? (size_t)t * 16384 : (size_t)(t & 1) * 16384;
    const size_t tn = rot ? (size_t)(t + 1) * 16384 : (size_t)((t & 1) ^ 1) * 16384;

#pragma unroll
    for (int i = 0; i < 16; ++i) { acc0[i] = 0.f; acc1[i] = 0.f; }

    // ---- x-phase: burst-load 16 A-frags, then MFMA against parked Bx ----
    {
      const uint4* ax = xA4 + (size_t)t * 8192 + xaOff;
      v8s xr[16];
#pragma unroll
      for (int kb = 0; kb < 16; ++kb)
        xr[kb] = __builtin_bit_cast(v8s, ax[kb * 64]);
#pragma unroll
      for (int kb = 0; kb < 16; ++kb) {
        if (kb & 1) acc1 = __builtin_amdgcn_mfma_f32_32x32x16_bf16(xr[kb], Bx[kb], acc1, 0, 0, 0);
        else        acc0 = __builtin_amdgcn_mfma_f32_32x32x16_bf16(xr[kb], Bx[kb], acc0, 0, 0, 0);
      }
    }

    // ---- rq-group wait: PER-WAVE lane0 poll, no barrier. Reconvergence
    // gates the wave; each wave issues its h-loads the moment it detects. ----
    if (t > 0) {
      if (lane == 0) {
        u32 spins = 0;
        while (__hip_atomic_load(&barrier[rq * 64], __ATOMIC_RELAXED,
                                 __HIP_MEMORY_SCOPE_AGENT) < 64u * (u32)t) {
          if (++spins > (1u << 22)) break;   // safety valve
        }
      }
      // implicit reconvergence: whole wave proceeds after lane0 exits
    }

    // ---- h-phase: burst-load 32 A-frags, MFMA against parked Bh ----
    {
      const uint4* ah = HA4 + tb + haOff;
      v8s hr[32];
      if (rot) {
#pragma unroll
        for (int kb = 0; kb < 32; ++kb)
          hr[kb] = __builtin_bit_cast(v8s, ah[kb * 64]);
      } else {
#pragma unroll
        for (int kb = 0; kb < 32; ++kb)
          hr[kb] = __builtin_bit_cast(v8s, uc_ld16((const u16*)(ah + kb * 64)));
      }
#pragma unroll
      for (int kb = 0; kb < 32; ++kb) {
        if (kb & 1) acc1 = __builtin_amdgcn_mfma_f32_32x32x16_bf16(hr[kb], Bh[kb], acc1, 0, 0, 0);
        else        acc0 = __builtin_amdgcn_mfma_f32_32x32x16_bf16(hr[kb], Bh[kb], acc0, 0, 0, 0);
      }
    }

    // ---- cross-kh reduce, gates, state update ----
    float aT[16];
#pragma unroll
    for (int i = 0; i < 16; ++i) aT[i] = acc0[i] + acc1[i];
    {
      int h2 = 1 - kh;
#pragma unroll
      for (int i = 0; i < 8; ++i)
        scr[ct * 1024 + h2 * 512 + i * 64 + lane] = aT[h2 * 8 + i];
    }
    __syncthreads();

    const bool lastT = (t == S_ - 1);
#pragma unroll
    for (int i = 0; i < 8; ++i) {
      int r = kh * 8 + i;
      float pre = aT[r] + scr[ct * 1024 + kh * 512 + i * 64 + lane] + bias;
      // gate 2 -> tanh (overflow-safe), others -> sigmoid
      float e = __expf((gate == 2) ? (2.f * pre) : (-pre));
      float act = (gate == 2) ? (1.f - 2.f / (e + 1.f)) : (1.f / (1.f + e));
      int qb = lane & ~3;   // quad holds f,i,g,o of one (row,unit)
      float F = __shfl(act, qb + 0, 64);
      float I = __shfl(act, qb + 1, 64);
      float G = __shfl(act, qb + 2, 64);
      float O = __shfl(act, qb + 3, 64);
      float cn = fmaf(F, c[i], I * G);
      c[i] = cn;
      float e2 = __expf(2.f * cn);
      float hv = O * (1.f - 2.f / (e2 + 1.f));
      if (gate == 0) {
        int rowL = (r & 3) + ((r >> 2) << 3) + (kgsel << 2);   // 0..31
        hstage[rowL * 16 + unitL] = f2bf(hv);
        if (lastT) {
          int grow = rq * 32 + rowL;
          int gunit = cg * 16 + unitL;
          out[65536 + grow * H_ + gunit] = hv;    // h output (fp32)
          out[196608 + grow * H_ + gunit] = cn;   // c output (fp32)
        }
      }
    }
    __syncthreads();

    // ---- publish: wave0 only (other waves run ahead to x of t+1; the
    // per-wave wait of t+1 cannot pass until our flag-add lands, which is
    // after wave0's hstage read -- hstage/scr reuse stays ordered). ----
    if (tid < 64) {
      int row = tid >> 1, u16sel = tid & 1;
      uint4 v = ((const uint4*)hstage)[tid];
      uc_st16((u16*)(HA4 + tn + rq * 4096 + (size_t)(2 * cg + u16sel) * 32 + row), v);
      asm volatile("s_waitcnt vmcnt(0)" ::: "memory");
      if (tid == 0)
        atomicAdd(&barrier[rq * 64], 1u);
    }
  }

  // ---- full barrier (4 aggregated counters), then out = h @ Why^T + b ----
  {
    if (tid < 4) {
      u32 spins = 0;
      while (__hip_atomic_load(&barrier[tid * 64], __ATOMIC_RELAXED,
                               __HIP_MEMORY_SCOPE_AGENT) < 64u * (u32)S_) {
        __builtin_amdgcn_s_sleep(2);
        if (++spins > (1u << 22)) break;
      }
    }
  }
  __syncthreads();

  if (blockIdx.x < 32) {
    const int wg = blockIdx.x;
    const uint4* HF = HA4 + (rot ? (size_t)S_ * 16384 : 0);
    const int l15 = lane & 15;
    const int l4 = lane >> 4;
    const int colO = (wg << 4) + l15;
    v4f o0, o1;
#pragma unroll
    for (int i = 0; i < 4; ++i) { o0[i] = 0.f; o1[i] = 0.f; }
#pragma unroll 4
    for (int kc = 0; kc < 32; ++kc) {
      v8s bfrag = *(const v8s*)(WhyT + (size_t)colO * H_ + kc * 32 + (l4 << 3));
      size_t i0 = (size_t)w * 4096 + kc * 128 + l4 * 32 + l15;
      v8s a0, a1;
      if (rot) {
        a0 = __builtin_bit_cast(v8s, HF[i0]);
        a1 = __builtin_bit_cast(v8s, HF[i0 + 16]);
      } else {
        a0 = __builtin_bit_cast(v8s, uc_ld16((const u16*)(HF + i0)));
        a1 = __builtin_bit_cast(v8s, uc_ld16((const u16*)(HF + i0 + 16)));
      }
      o0 = __builtin_amdgcn_mfma_f32_16x16x32_bf16(a0, bfrag, o0, 0, 0, 0);
      o1 = __builtin_amdgcn_mfma_f32_16x16x32_bf16(a1, bfrag, o1, 0, 0, 0);
    }
    float bO = WhyB[colO];
#pragma unroll
    for (int r2 = 0; r2 < 4; ++r2) {
      int row = (w << 5) + (l4 << 2) + r2;
      out[row * O_ + colO] = o0[r2] + bO;
      out[(row + 16) * O_ + colO] = o1[r2] + bO;
    }
  }
}

// ------------------------------------------------------------- launch ----
extern "C" void kernel_launch(void* const* d_in, const int* in_sizes, int n_in,
                              void* d_out, int out_size, void* d_ws, size_t ws_size,
                              hipStream_t stream) {
  const float* x    = (const float*)d_in[0];
  const float* Wxf  = (const float*)d_in[1];
  const float* bf_  = (const float*)d_in[2];
  const float* Whf  = (const float*)d_in[3];
  const float* Wxi  = (const float*)d_in[4];
  const float* bi_  = (const float*)d_in[5];
  const float* Whi  = (const float*)d_in[6];
  const float* Wxg  = (const float*)d_in[7];
  const float* bg_  = (const float*)d_in[8];
  const float* Whg  = (const float*)d_in[9];
  const float* Wxo  = (const float*)d_in[10];
  const float* bo_  = (const float*)d_in[11];
  const float* Who  = (const float*)d_in[12];
  const float* Why  = (const float*)d_in[13];
  const float* Whyb = (const float*)d_in[14];

  char* ws = (char*)d_ws;
  u16*   xtp  = (u16*)(ws);                    // xA: 33,554,432 B
  u16*   Wcp  = (u16*)(ws + 33554432);         // WcF: 12,582,912 B
  float* bcp  = (float*)(ws + 46137344);       //     16,384 B
  u16*   WhyT = (u16*)(ws + 46153728);         //  1,048,576 B
  u32*   barp = (u32*)(ws + 47202304);         //      1,024 B (4 padded counters)
  u16*   hbuf = (u16*)(ws + 47203328);         // hA: rot 257*256KB else 512KB
  float* outp = (float*)d_out;

  const size_t need_rot = 47203328ull + 257ull * 262144ull;  // ~114.6 MB
  int rot = (ws_size >= need_rot) ? 1 : 0;

  lstm_prep<<<dim3(1024), dim3(256), 0, stream>>>(
      x, Whf, Whi, Whg, Who, Wxf, Wxi, Wxg, Wxo,
      bf_, bi_, bg_, bo_, Why, xtp, Wcp, bcp, WhyT, hbuf, barp);

  lstm_seq<<<dim3(256), dim3(256), 0, stream>>>(
      xtp, Wcp, bcp, hbuf, WhyT, Whyb, outp, barp, rot);
}